// Round 9
// baseline (30.746 us; speedup 1.0000x reference)
//
#include <hip/hip_runtime.h>
#include <hip/hip_bf16.h>
#include <math.h>

// Inverse Radon backprojection: LDS angle-windows + antipodal pairing +
// 4-way angle split + readlane-distributed per-angle constants.
// sinogram: (B, N=180, W=512) fp32;  angles: (N,) degrees fp32
// output:   (B, 1, 512, 512) fp32
//
// Structure: one block = 16x16 tile of pixel PAIRS, 1024 threads = 4 threads
// per pair; quarter q sums angles [45q,45q+45), LDS tree-combine at the end.
// 512 blocks -> 2 blocks/CU x 16 waves = 32 waves/CU.
//
// r8 lesson: inner loop was LDS-pipe-bound (3 LDS instr/iter ~ 26 cyc vs
// ~24 VALU ~ 12 cyc). The per-iter uniform s_c broadcast (ds_read_b128) is
// moved OFF the LDS pipe: each lane preloads one angle's float4 constants,
// and the loop fetches them via v_readlane (VALU pipe, uniform lane index).
// Remaining LDS/iter: just the 2 ds_read2_b32 taps.
//
// Inner-loop identities (validated r2/r6/r7/r8):
//  - taps from zero-filled 32-float windows == reference mask*gather exactly
//  - yw = sat(iy+1) * sat(512-iy)   (saturate == med3 clamp, validated)
//  - mirror: ix' = 511-ix, yw' == yw; rebase folded into fma addends.

#define IRD_W 512
#define IRD_N 180
#define WIN   32
#define QN    45                      // angles per thread-quarter
#define IRD_STEP (2.0f / 511.0f)

__device__ __forceinline__ float rlane(float v, int k) {
    return __builtin_bit_cast(float,
        __builtin_amdgcn_readlane(__builtin_bit_cast(int, v), k));
}

__global__ __launch_bounds__(1024, 8) void iradon_tile4_kernel(
    const float* __restrict__ sino,    // B*N*W
    const float* __restrict__ angles,  // N
    float* __restrict__ out)           // B*H*W
{
    __shared__ float4 s_c[IRD_N];            // {ch, sh, 255.5-baseA, 511-baseA-baseB}
    __shared__ int2   s_base[IRD_N];         // {baseA, baseB}
    __shared__ float  s_win[IRD_N][2 * WIN]; // [angle][A-window | B-window]
    __shared__ float  s_redA[3][256];        // quarter partials (q=1..3)
    __shared__ float  s_redB[3][256];

    const int tid = threadIdx.x;
    const int x0 = (blockIdx.x & 31) << 4;   // tile origin, top half
    const int y0 = (blockIdx.x >> 5) << 4;   // y0 in [0,256)
    const int b  = blockIdx.y;

    const float h = 255.5f;
    const float xs0 = -1.0f + (float)x0 * IRD_STEP;
    const float ys0 = -1.0f + (float)y0 * IRD_STEP;
    const float xs1 = xs0 + 15.0f * IRD_STEP;
    const float ys1 = ys0 + 15.0f * IRD_STEP;

    if (tid < IRD_N) {
        float th = angles[tid] * 0.017453292519943295f;
        float sv, cv;
        sincosf(th, &sv, &cv);
        const float ch = cv * h, sh = sv * h;
        // tile-corner extrema of ix (linear in x,y -> corners suffice)
        const float cx0 = ch * xs0, cx1 = ch * xs1;
        const float sy0 = sh * ys0, sy1 = sh * ys1;
        const float minA = fminf(cx0, cx1) + fminf(sy0, sy1) + h;
        const float maxA = fmaxf(cx0, cx1) + fmaxf(sy0, sy1) + h;
        const int baseA = (int)floorf(minA) - 1;
        const int baseB = (int)floorf(511.0f - maxA) - 1;
        s_c[tid] = make_float4(ch, sh, h - (float)baseA,
                               (float)(511 - baseA - baseB));
        s_base[tid] = make_int2(baseA, baseB);
    }
    __syncthreads();

    // Cooperative window staging: within each 64-slot group, lanes 0-31 -> A
    // window, 32-63 -> B window. Coalesced; OOB -> 0 (== reference masks).
    const float* __restrict__ sb = sino + (size_t)b * (IRD_N * IRD_W);
    for (int idx = tid; idx < IRD_N * 2 * WIN; idx += 1024) {
        const int n    = idx >> 6;
        const int slot = idx & 63;
        const int base = (slot < WIN) ? s_base[n].x : s_base[n].y;
        const int src  = base + (slot & (WIN - 1));
        float v = 0.0f;
        if ((unsigned)src < IRD_W) v = sb[n * IRD_W + src];
        s_win[n][slot] = v;
    }
    __syncthreads();

    const int p = tid & 255;                 // pixel slot in tile
    const int q = tid >> 8;                  // angle quarter 0..3
    const int n0 = q * QN;
    const int x = x0 + (p & 15);
    const int y = y0 + (p >> 4);
    const float xs = -1.0f + (float)x * IRD_STEP;
    const float ys = -1.0f + (float)y * IRD_STEP;
    const float xsn = -xs;

    // lane l of each wave holds angle (n0+l)'s constants (l>=QN: clamped dup)
    const int lane = tid & 63;
    const float4 c4 = s_c[n0 + (lane < QN ? lane : QN - 1)];

    float accA = 0.0f, accB = 0.0f;

    #pragma unroll 5
    for (int k = 0; k < QN; ++k) {
        const float ch = rlane(c4.x, k);
        const float sh = rlane(c4.y, k);
        const float zA = rlane(c4.z, k);
        const float wC = rlane(c4.w, k);
        const int n = n0 + k;

        const float ixr  = fmaf(ch, xs, fmaf(sh, ys, zA));    // ix - baseA
        const float iy   = fmaf(ch, ys, fmaf(sh, xsn, h));    // absolute
        const float ixmr = wC - ixr;                          // (511-ix)-baseB

        const float fA  = floorf(ixr);
        const float w1A = ixr - fA;
        const int   iA  = (int)fA;            // in [1, 24] -> in-window

        const float fB  = floorf(ixmr);
        const float w1B = ixmr - fB;
        const int   iB  = (int)fB;            // in [1, 24]

        const float g0A = s_win[n][iA];
        const float g1A = s_win[n][iA + 1];
        const float g0B = s_win[n][WIN + iB];
        const float g1B = s_win[n][WIN + iB + 1];

        const float a  = __saturatef(iy + 1.0f);
        const float bb = __saturatef(512.0f - iy);
        const float yw = a * bb;

        accA = fmaf(fmaf(w1A, g1A - g0A, g0A), yw, accA);
        accB = fmaf(fmaf(w1B, g1B - g0B, g0B), yw, accB);
    }

    if (q != 0) {
        s_redA[q - 1][p] = accA;
        s_redB[q - 1][p] = accB;
    }
    __syncthreads();

    if (q == 0) {
        accA = ((accA + s_redA[0][p]) + s_redA[1][p]) + s_redA[2][p];
        accB = ((accB + s_redB[0][p]) + s_redB[1][p]) + s_redB[2][p];
        const int ob = b << 18;
        out[ob + (y << 9) + x]                 = accA * (1.0f / 180.0f);
        out[ob + ((511 - y) << 9) + (511 - x)] = accB * (1.0f / 180.0f);
    }
}

extern "C" void kernel_launch(void* const* d_in, const int* in_sizes, int n_in,
                              void* d_out, int out_size, void* d_ws, size_t ws_size,
                              hipStream_t stream) {
    const float* sino = (const float*)d_in[0];
    const float* angles = (const float*)d_in[1];
    float* out = (float*)d_out;

    const int B = out_size >> 18;            // H*W == 2^18
    dim3 grid(512, B > 0 ? B : 1);           // 32x16 tiles cover the top half
    iradon_tile4_kernel<<<grid, 1024, 0, stream>>>(sino, angles, out);
}

// Round 10
// 24.278 us; speedup vs baseline: 1.2664x; 1.2664x over previous
//
#include <hip/hip_runtime.h>
#include <hip/hip_bf16.h>
#include <hip/hip_fp16.h>
#include <math.h>

// Inverse Radon backprojection: fp16 quad windows + antipodal pairing +
// 4-way angle split. sinogram: (B,180,512) fp32; angles: (N,) deg; out (B,1,512,512).
//
// Structure: block = 16x16 tile of pixel PAIRS, 1024 threads = 4/pair
// (quarter q sums angles [45q,45q+45)), LDS tree-combine. 512 blocks ->
// 2 blocks/CU x 16 waves = 32 waves/CU.
//
// r8: loop was LDS-pipe-bound (1 b128 const + 2 read2 taps ~ 28 cyc/iter).
// r9: readlane constants REGRESSED (VALU->SGPR hazards) -- reverted.
// r10 changes, both LDS cuts:
//  - fp16 QUAD window: slot i of angle n holds {s[gi],s[gi+1],s[510-gi],
//    s[511-gi]} (gi = baseA+i) as 4xfp16 in 8B -> ONE ds_read_b64 gives all
//    4 taps of both mirrored pixels. Mirror identity (exact, both int and
//    frac ix): valB = v + w1A*(u-v) where u=s[510-gi], v=s[511-gi] -- the
//    whole B-side floor/addr chain is gone.
//  - constants split: s_cs[n]=(ch,sh) float2 + s_off[n]=int; adjacent iters
//    merge into ds_read2_b64 / ds_read2_b32 under unroll.
// fp16 tap error ~|g|*2^-11, /180 at the end -> ~1e-4 added output error.
//
// Validated identities (r2..r8): zero-filled windows == reference mask*
// gather; yw = sat(iy+1)*sat(512-iy); mirror ix'=511-ix, yw'==yw.

#define IRD_W 512
#define IRD_N 180
#define WIN   32
#define QN    45
#define IRD_STEP (2.0f / 511.0f)

__global__ __launch_bounds__(1024, 8) void iradon_quad_kernel(
    const float* __restrict__ sino,    // B*N*W
    const float* __restrict__ angles,  // N
    float* __restrict__ out)           // B*H*W
{
    __shared__ float2 s_cs[IRD_N];           // {ch, sh}
    __shared__ int    s_off[IRD_N];          // n*32 - baseA (slot rebase)
    __shared__ int    s_base[IRD_N];         // baseA
    __shared__ uint2  s_quad[IRD_N * WIN];   // fp16 quad taps, 8B/slot
    __shared__ float  s_redA[3][256];
    __shared__ float  s_redB[3][256];

    const int tid = threadIdx.x;
    const int x0 = (blockIdx.x & 31) << 4;
    const int y0 = (blockIdx.x >> 5) << 4;   // y0 in [0,256)
    const int b  = blockIdx.y;

    const float h = 255.5f;
    const float xs0 = -1.0f + (float)x0 * IRD_STEP;
    const float ys0 = -1.0f + (float)y0 * IRD_STEP;
    const float xs1 = xs0 + 15.0f * IRD_STEP;
    const float ys1 = ys0 + 15.0f * IRD_STEP;

    if (tid < IRD_N) {
        float th = angles[tid] * 0.017453292519943295f;
        float sv, cv;
        sincosf(th, &sv, &cv);
        const float ch = cv * h, sh = sv * h;
        const float cx0 = ch * xs0, cx1 = ch * xs1;
        const float sy0 = sh * ys0, sy1 = sh * ys1;
        const float minA = fminf(cx0, cx1) + fminf(sy0, sy1) + h;
        const int baseA = (int)floorf(minA) - 1;
        s_cs[tid]  = make_float2(ch, sh);
        s_off[tid] = (tid << 5) - baseA;
        s_base[tid] = baseA;
    }
    __syncthreads();

    // Stage fp16 quad windows: slot (n,i) <- {s[gi],s[gi+1],s[510-gi],
    // s[511-gi]}, gi = baseA+i, zero-filled OOB (== reference masks).
    const float* __restrict__ sb = sino + (size_t)b * (IRD_N * IRD_W);
    for (int idx = tid; idx < IRD_N * WIN; idx += 1024) {
        const int n  = idx >> 5;
        const int i  = idx & (WIN - 1);
        const int gi = s_base[n] + i;
        const float* __restrict__ row = sb + n * IRD_W;
        const float g0 = ((unsigned)gi       < IRD_W) ? row[gi]       : 0.0f;
        const float g1 = ((unsigned)(gi + 1) < IRD_W) ? row[gi + 1]   : 0.0f;
        const float u  = ((unsigned)(510-gi) < IRD_W) ? row[510 - gi] : 0.0f;
        const float v  = ((unsigned)(511-gi) < IRD_W) ? row[511 - gi] : 0.0f;
        const __half2 hA  = __float22half2_rn(make_float2(g0, g1));
        const __half2 hUV = __float22half2_rn(make_float2(u,  v));
        s_quad[idx] = make_uint2(__builtin_bit_cast(unsigned, hA),
                                 __builtin_bit_cast(unsigned, hUV));
    }
    __syncthreads();

    const int p = tid & 255;
    const int q = tid >> 8;
    const int n0 = q * QN;
    const int x = x0 + (p & 15);
    const int y = y0 + (p >> 4);
    const float xs = -1.0f + (float)x * IRD_STEP;
    const float ys = -1.0f + (float)y * IRD_STEP;
    const float xsn = -xs;

    float accA = 0.0f, accB = 0.0f;

    #pragma unroll 5
    for (int k = 0; k < QN; ++k) {
        const int n = n0 + k;
        const float2 cs = s_cs[n];
        const int   off = s_off[n];

        const float ix = fmaf(cs.x, xs, fmaf(cs.y, ys, h));   // absolute
        const float iy = fmaf(cs.x, ys, fmaf(cs.y, xsn, h));

        const float fg = floorf(ix);
        const float w1 = ix - fg;
        const int   gi = (int)fg;                 // slot = off+gi in [1,24]+n*32

        const uint2 q2 = s_quad[off + gi];        // one b64: all 4 taps
        const float2 a  = __half22float2(__builtin_bit_cast(__half2, q2.x));
        const float2 uv = __half22float2(__builtin_bit_cast(__half2, q2.y));

        const float yw = __saturatef(iy + 1.0f) * __saturatef(512.0f - iy);

        const float valA = fmaf(w1, a.y - a.x, a.x);
        const float valB = fmaf(w1, uv.x - uv.y, uv.y);
        accA = fmaf(valA, yw, accA);
        accB = fmaf(valB, yw, accB);
    }

    if (q != 0) {
        s_redA[q - 1][p] = accA;
        s_redB[q - 1][p] = accB;
    }
    __syncthreads();

    if (q == 0) {
        accA = ((accA + s_redA[0][p]) + s_redA[1][p]) + s_redA[2][p];
        accB = ((accB + s_redB[0][p]) + s_redB[1][p]) + s_redB[2][p];
        const int ob = b << 18;
        out[ob + (y << 9) + x]                 = accA * (1.0f / 180.0f);
        out[ob + ((511 - y) << 9) + (511 - x)] = accB * (1.0f / 180.0f);
    }
}

extern "C" void kernel_launch(void* const* d_in, const int* in_sizes, int n_in,
                              void* d_out, int out_size, void* d_ws, size_t ws_size,
                              hipStream_t stream) {
    const float* sino = (const float*)d_in[0];
    const float* angles = (const float*)d_in[1];
    float* out = (float*)d_out;

    const int B = out_size >> 18;            // H*W == 2^18
    dim3 grid(512, B > 0 ? B : 1);
    iradon_quad_kernel<<<grid, 1024, 0, stream>>>(sino, angles, out);
}